// Round 1
// baseline (2012.131 us; speedup 1.0000x reference)
//
#include <hip/hip_runtime.h>
#include <hip/hip_bf16.h>

#define EPS_F 1e-30f

// ---------------------------------------------------------------------------
// Kernel 1: per-edge precompute.
// 16 lanes cooperate on one edge: each lane loads float4 of feats and W,
// 4-step shuffle reduction, lane 0 writes rewards / M / p.
// ---------------------------------------------------------------------------
__global__ void edge_precompute(const float* __restrict__ feats,
                                const int* __restrict__ src,
                                const int* __restrict__ dst,
                                const float* __restrict__ scales,
                                const float* __restrict__ W,
                                const float* __restrict__ bptr,
                                float* __restrict__ rewards,
                                float* __restrict__ Mout,
                                float* __restrict__ pout,
                                int E) {
    int tid = blockIdx.x * blockDim.x + threadIdx.x;
    int e = tid >> 4;
    int lane = threadIdx.x & 15;
    if (e >= E) return;

    const float4 w4 = reinterpret_cast<const float4*>(W)[lane];
    const float4 f4 = reinterpret_cast<const float4*>(feats + (size_t)e * 64)[lane];
    float s = f4.x * w4.x + f4.y * w4.y + f4.z * w4.z + f4.w * w4.w;

    // butterfly reduce across the 16-lane group (masks stay inside the group)
    s += __shfl_xor(s, 1);
    s += __shfl_xor(s, 2);
    s += __shfl_xor(s, 4);
    s += __shfl_xor(s, 8);

    if (lane == 0) {
        float t = s + bptr[0];
        // stable softplus: max(t,0) + log1p(exp(-|t|))
        float sp = fmaxf(t, 0.0f) + log1pf(expf(-fabsf(t)));
        float r = -sp;
        int sj = src[e];
        int di = dst[e];
        float mu_i = scales[di];
        float mu_j = scales[sj];
        rewards[e] = r;
        Mout[e] = expf(r / mu_i);
        pout[e] = mu_j / mu_i;
    }
}

// ---------------------------------------------------------------------------
// x_next = sink_mask  (the "+ b" term of the fixed-point map)
// ---------------------------------------------------------------------------
__global__ void node_init(const float* __restrict__ sink,
                          float* __restrict__ x, int N) {
    int i = blockIdx.x * blockDim.x + threadIdx.x;
    if (i < N) x[i] = sink[i];
}

// ---------------------------------------------------------------------------
// One Jacobi step: x_next[dst] += M * x_cur[src]^p  (atomic scatter-add)
// ---------------------------------------------------------------------------
__global__ void edge_iter(const int* __restrict__ src,
                          const int* __restrict__ dst,
                          const float* __restrict__ M,
                          const float* __restrict__ p,
                          const float* __restrict__ xin,
                          float* __restrict__ xout,
                          int E) {
    int e = blockIdx.x * blockDim.x + threadIdx.x;
    if (e >= E) return;
    float xv = xin[src[e]];
    float val = M[e] * powf(xv, p[e]);
    atomicAdd(xout + dst[e], val);
}

// ---------------------------------------------------------------------------
// values = log(max(x, EPS))
// ---------------------------------------------------------------------------
__global__ void node_final(const float* __restrict__ x,
                           float* __restrict__ values, int N) {
    int i = blockIdx.x * blockDim.x + threadIdx.x;
    if (i < N) values[i] = logf(fmaxf(x[i], EPS_F));
}

// ---------------------------------------------------------------------------
// edge_probs = (x[dst] > 0) ? M * x[src]^p / max(x[dst], EPS) : 0
// ---------------------------------------------------------------------------
__global__ void edge_final(const int* __restrict__ src,
                           const int* __restrict__ dst,
                           const float* __restrict__ M,
                           const float* __restrict__ p,
                           const float* __restrict__ x,
                           float* __restrict__ eprobs,
                           int E) {
    int e = blockIdx.x * blockDim.x + threadIdx.x;
    if (e >= E) return;
    float msg = M[e] * powf(x[src[e]], p[e]);
    float denom = x[dst[e]];
    eprobs[e] = (denom > 0.0f) ? msg / fmaxf(denom, EPS_F) : 0.0f;
}

extern "C" void kernel_launch(void* const* d_in, const int* in_sizes, int n_in,
                              void* d_out, int out_size, void* d_ws, size_t ws_size,
                              hipStream_t stream) {
    const int*   eidx   = (const int*)d_in[0];    // [2, E]
    const float* feats  = (const float*)d_in[1];  // [E, 64]
    const float* scales = (const float*)d_in[2];  // [N]
    const float* sink   = (const float*)d_in[3];  // [N]
    const float* W      = (const float*)d_in[4];  // [64]
    const float* b      = (const float*)d_in[5];  // [1]

    const int E = in_sizes[0] / 2;
    const int N = in_sizes[2];
    const int N_ITERS = 40;

    const int* src = eidx;       // edge_index[0]
    const int* dst = eidx + E;   // edge_index[1]

    float* out     = (float*)d_out;
    float* rewards = out;            // [E]
    float* values  = out + E;        // [N]
    float* eprobs  = out + E + N;    // [E]

    float* M  = (float*)d_ws;        // [E]
    float* p  = M + E;               // [E]
    float* x0 = p + E;               // [N]
    float* x1 = x0 + N;              // [N]

    // --- per-edge precompute (rewards, M, p) -------------------------------
    {
        long long threads = (long long)E * 16;
        int grid = (int)((threads + 255) / 256);
        edge_precompute<<<grid, 256, 0, stream>>>(feats, src, dst, scales, W, b,
                                                  rewards, M, p, E);
    }

    const int nodeGrid = (N + 255) / 256;
    const int edgeGrid = (E + 255) / 256;

    // --- x = sink_mask ------------------------------------------------------
    node_init<<<nodeGrid, 256, 0, stream>>>(sink, x0, N);

    float* xc = x0;
    float* xn = x1;
    for (int it = 0; it < N_ITERS; ++it) {
        node_init<<<nodeGrid, 256, 0, stream>>>(sink, xn, N);
        edge_iter<<<edgeGrid, 256, 0, stream>>>(src, dst, M, p, xc, xn, E);
        float* tmp = xc; xc = xn; xn = tmp;
    }

    // --- outputs ------------------------------------------------------------
    node_final<<<nodeGrid, 256, 0, stream>>>(xc, values, N);
    edge_final<<<edgeGrid, 256, 0, stream>>>(src, dst, M, p, xc, eprobs, E);
}